// Round 1
// baseline (216.649 us; speedup 1.0000x reference)
//
#include <hip/hip_runtime.h>
#include <cstdint>
#include <cstddef>

typedef __attribute__((ext_vector_type(8))) short bf16x8;
typedef __attribute__((ext_vector_type(4))) float f32x4;
typedef __attribute__((ext_vector_type(8))) unsigned short ushort8;
typedef __attribute__((ext_vector_type(4))) unsigned short ushort4v;

#define B_SZ   512
#define D1_IN  40
#define T_DIM  1024
#define D1_OUT 120
#define D2_OUT 64
#define M_ROWS (B_SZ * D1_IN)            // 20480
#define OUT0_SZ (B_SZ * D1_OUT * D2_OUT) // 3932160

// ---- helpers ----
__device__ __forceinline__ unsigned short f2bf(float f) {
    unsigned int u = __float_as_uint(f);
    u += 0x7FFFu + ((u >> 16) & 1u);   // RNE
    return (unsigned short)(u >> 16);
}
__device__ __forceinline__ float bf2f(unsigned short h) {
    return __uint_as_float(((unsigned int)h) << 16);
}
__device__ __forceinline__ void gld16(const unsigned short* g, unsigned short* l) {
    __builtin_amdgcn_global_load_lds(
        (const __attribute__((address_space(1))) unsigned int*)g,
        (__attribute__((address_space(3))) unsigned int*)l, 16, 0, 0);
}

// ---- convert x (fp32) -> xb (bf16) ----
__global__ __launch_bounds__(256) void k_cvt_x(const float* __restrict__ X,
                                               unsigned short* __restrict__ Y, int n4) {
    int stride = gridDim.x * blockDim.x;
    for (int i = blockIdx.x * blockDim.x + threadIdx.x; i < n4; i += stride) {
        float4 v = ((const float4*)X)[i];
        ushort4v o;
        o.x = f2bf(v.x); o.y = f2bf(v.y); o.z = f2bf(v.z); o.w = f2bf(v.w);
        ((ushort4v*)Y)[i] = o;
    }
}

// ---- transpose src(RxC fp32) -> dst(CxR bf16) ----
__global__ __launch_bounds__(256) void k_transpose_bf(const float* __restrict__ src,
                                                      unsigned short* __restrict__ dst,
                                                      int R, int C) {
    __shared__ float tile[32][33];
    int c0 = blockIdx.x * 32, r0 = blockIdx.y * 32;
    int tx = threadIdx.x & 31, ty = threadIdx.x >> 5;  // 32x8
    #pragma unroll
    for (int i = 0; i < 4; i++)
        tile[ty + i * 8][tx] = src[(size_t)(r0 + ty + i * 8) * C + c0 + tx];
    __syncthreads();
    #pragma unroll
    for (int i = 0; i < 4; i++)
        dst[(size_t)(c0 + ty + i * 8) * R + r0 + tx] = f2bf(tile[tx][ty + i * 8]);
}

// ---- W1 (120x40 fp32) -> padded bf16 (128x64, zeros) ----
__global__ __launch_bounds__(256) void k_w1pad(const float* __restrict__ W1,
                                               unsigned short* __restrict__ w1p) {
    for (int i = threadIdx.x; i < 128 * 64; i += 256) {
        int o = i >> 6, f = i & 63;
        w1p[i] = (o < D1_OUT && f < D1_IN) ? f2bf(W1[o * D1_IN + f]) : (unsigned short)0;
    }
}

// ---- GEMM1: E(bf16) = xb(20480x1024) @ Wt^T  (Wt is [n][k] = W[k][n]) ----
__global__ __launch_bounds__(256) void k_gemm1(const unsigned short* __restrict__ xb,
                                               const unsigned short* __restrict__ wt,
                                               unsigned short* __restrict__ E) {
    __shared__ unsigned short As[128 * 32];
    __shared__ unsigned short Bs[128 * 32];
    int bm = blockIdx.x >> 3, bn = blockIdx.x & 7;   // 160 x 8
    int tid = threadIdx.x, l = tid & 63, w = tid >> 6;
    int wr = w >> 1, wc = w & 1;
    int rr = l & 15, q = l >> 4;
    f32x4 acc[4][4] = {};
    for (int k0 = 0; k0 < T_DIM; k0 += 32) {
        __syncthreads();
        #pragma unroll
        for (int i = 0; i < 2; i++) {
            int ch = i * 256 + tid;            // 0..511, linear in lane per wave
            int r = ch >> 2, c = ch & 3;
            gld16(xb + (size_t)(bm * 128 + r) * T_DIM + k0 + c * 8, &As[ch * 8]);
            gld16(wt + (size_t)(bn * 128 + r) * T_DIM + k0 + c * 8, &Bs[ch * 8]);
        }
        __syncthreads();
        bf16x8 a[4], b[4];
        #pragma unroll
        for (int m = 0; m < 4; m++) a[m] = *(const bf16x8*)&As[(wr * 64 + m * 16 + rr) * 32 + q * 8];
        #pragma unroll
        for (int n = 0; n < 4; n++) b[n] = *(const bf16x8*)&Bs[(wc * 64 + n * 16 + rr) * 32 + q * 8];
        #pragma unroll
        for (int m = 0; m < 4; m++)
            #pragma unroll
            for (int n = 0; n < 4; n++)
                acc[m][n] = __builtin_amdgcn_mfma_f32_16x16x32_bf16(a[m], b[n], acc[m][n], 0, 0, 0);
    }
    #pragma unroll
    for (int m = 0; m < 4; m++)
        #pragma unroll
        for (int n = 0; n < 4; n++)
            #pragma unroll
            for (int j = 0; j < 4; j++) {
                int row = wr * 64 + m * 16 + q * 4 + j;
                int col = wc * 64 + n * 16 + rr;
                E[(size_t)(bm * 128 + row) * T_DIM + bn * 128 + col] = f2bf(acc[m][n][j]);
            }
}

// ---- softmax per row: A(fp32, to d_out) = softmax(E bf16) ----
__global__ __launch_bounds__(256) void k_softmax(const unsigned short* __restrict__ E,
                                                 float* __restrict__ A) {
    int row = blockIdx.x * 4 + (threadIdx.x >> 6);
    int l = threadIdx.x & 63;
    const ushort8* pe = (const ushort8*)(E + (size_t)row * T_DIM + l * 16);
    ushort8 u0 = pe[0], u1 = pe[1];
    float v[16];
    #pragma unroll
    for (int j = 0; j < 8; j++) { v[j] = bf2f(u0[j]); v[8 + j] = bf2f(u1[j]); }
    float m = v[0];
    #pragma unroll
    for (int j = 1; j < 16; j++) m = fmaxf(m, v[j]);
    for (int off = 32; off > 0; off >>= 1) m = fmaxf(m, __shfl_xor(m, off));
    float s = 0.f;
    #pragma unroll
    for (int j = 0; j < 16; j++) { v[j] = __expf(v[j] - m); s += v[j]; }
    for (int off = 32; off > 0; off >>= 1) s += __shfl_xor(s, off);
    float inv = 1.f / s;
    float4* pa = (float4*)(A + (size_t)row * T_DIM + l * 16);
    #pragma unroll
    for (int j = 0; j < 4; j++) {
        float4 o;
        o.x = v[j * 4 + 0] * inv; o.y = v[j * 4 + 1] * inv;
        o.z = v[j * 4 + 2] * inv; o.w = v[j * 4 + 3] * inv;
        pa[j] = o;
    }
}

// ---- fused: X_bar = W1@x[b] (MFMA), gate, out = X_tilde@W2 + B, relu ----
__global__ __launch_bounds__(256) void k_fused(const float* __restrict__ x,
                                               const unsigned short* __restrict__ w1p,
                                               const float* __restrict__ A,
                                               const unsigned short* __restrict__ w2t,
                                               const float* __restrict__ Bias,
                                               const float* __restrict__ lamp,
                                               float* __restrict__ out) {
    __shared__ unsigned short xst[64 * 72];   // [t][f], f-padded to 72, f>=40 zero
    __shared__ unsigned short xtl[128 * 72];  // [row][t], t-padded to 72
    int b = blockIdx.x;
    int tid = threadIdx.x, l = tid & 63, w = tid >> 6;
    int rr = l & 15, q = l >> 4;
    float lam = fminf(fmaxf(lamp[0], 0.f), 1.f);
    // hoist W1 A-fragments to registers (constant over chunks)
    bf16x8 aw[2][2];
    #pragma unroll
    for (int mi = 0; mi < 2; mi++)
        #pragma unroll
        for (int ks = 0; ks < 2; ks++)
            aw[mi][ks] = *(const bf16x8*)(w1p + (w * 32 + mi * 16 + rr) * 64 + ks * 32 + q * 8);
    f32x4 acc2[2][4] = {};
    for (int i = tid; i < 64 * 72; i += 256) xst[i] = 0;  // zero pad cols persist
    const float* Ab = A + (size_t)b * D1_IN * T_DIM;
    for (int tc = 0; tc < 16; tc++) {
        int t0 = tc * 64;
        __syncthreads();   // prev-chunk xst reads done
        for (int idx = tid; idx < 640; idx += 256) {
            int t4 = idx & 15, f = idx >> 4;
            float4 xv = *(const float4*)(x + ((size_t)b * D1_IN + f) * T_DIM + t0 + t4 * 4);
            xst[(t4 * 4 + 0) * 72 + f] = f2bf(xv.x);
            xst[(t4 * 4 + 1) * 72 + f] = f2bf(xv.y);
            xst[(t4 * 4 + 2) * 72 + f] = f2bf(xv.z);
            xst[(t4 * 4 + 3) * 72 + f] = f2bf(xv.w);
        }
        __syncthreads();
        // X_bar chunk via MFMA: rows [w*32, w*32+32), t [0,64)
        f32x4 acc1[2][4] = {};
        bf16x8 bx[4][2];
        #pragma unroll
        for (int ni = 0; ni < 4; ni++)
            #pragma unroll
            for (int ks = 0; ks < 2; ks++)
                bx[ni][ks] = *(const bf16x8*)&xst[(ni * 16 + rr) * 72 + ks * 32 + q * 8];
        #pragma unroll
        for (int mi = 0; mi < 2; mi++)
            #pragma unroll
            for (int ni = 0; ni < 4; ni++)
                #pragma unroll
                for (int ks = 0; ks < 2; ks++)
                    acc1[mi][ni] = __builtin_amdgcn_mfma_f32_16x16x32_bf16(aw[mi][ks], bx[ni][ks], acc1[mi][ni], 0, 0, 0);
        // gate: X_tilde = X_bar * (lam*A_g + (1-lam)); write own-wave rows to LDS
        #pragma unroll
        for (int mi = 0; mi < 2; mi++)
            #pragma unroll
            for (int ni = 0; ni < 4; ni++)
                #pragma unroll
                for (int j = 0; j < 4; j++) {
                    int row = w * 32 + mi * 16 + q * 4 + j;
                    int t = ni * 16 + rr;
                    float g = lam * Ab[(size_t)(row % D1_IN) * T_DIM + t0 + t] + (1.f - lam);
                    xtl[row * 72 + t] = f2bf(acc1[mi][ni][j] * g);
                }
        // GEMM2 accumulate (same-wave LDS RAW: DS ops in-order per wave)
        #pragma unroll
        for (int ks = 0; ks < 2; ks++) {
            bf16x8 a2[2], b2[4];
            #pragma unroll
            for (int mi = 0; mi < 2; mi++)
                a2[mi] = *(const bf16x8*)&xtl[(w * 32 + mi * 16 + rr) * 72 + ks * 32 + q * 8];
            #pragma unroll
            for (int ni = 0; ni < 4; ni++)
                b2[ni] = *(const bf16x8*)(w2t + (size_t)(ni * 16 + rr) * T_DIM + t0 + ks * 32 + q * 8);
            #pragma unroll
            for (int mi = 0; mi < 2; mi++)
                #pragma unroll
                for (int ni = 0; ni < 4; ni++)
                    acc2[mi][ni] = __builtin_amdgcn_mfma_f32_16x16x32_bf16(a2[mi], b2[ni], acc2[mi][ni], 0, 0, 0);
        }
    }
    #pragma unroll
    for (int mi = 0; mi < 2; mi++)
        #pragma unroll
        for (int ni = 0; ni < 4; ni++)
            #pragma unroll
            for (int j = 0; j < 4; j++) {
                int row = w * 32 + mi * 16 + q * 4 + j;
                if (row < D1_OUT) {
                    int col = ni * 16 + rr;
                    float v = acc2[mi][ni][j] + Bias[row * D2_OUT + col];
                    out[((size_t)b * D1_OUT + row) * D2_OUT + col] = fmaxf(v, 0.f);
                }
            }
}

extern "C" void kernel_launch(void* const* d_in, const int* in_sizes, int n_in,
                              void* d_out, int out_size, void* d_ws, size_t ws_size,
                              hipStream_t stream) {
    const float* x    = (const float*)d_in[0];
    const float* W1   = (const float*)d_in[1];
    const float* W    = (const float*)d_in[2];
    const float* W2   = (const float*)d_in[3];
    const float* Bias = (const float*)d_in[4];
    const float* lam  = (const float*)d_in[5];
    float* out = (float*)d_out;
    float* A   = out + OUT0_SZ;                    // second output region

    char* ws = (char*)d_ws;
    unsigned short* xb  = (unsigned short*)(ws);                 // 41,943,040 B
    unsigned short* wt  = (unsigned short*)(ws + 41943040);      //  2,097,152 B
    unsigned short* w2t = (unsigned short*)(ws + 44040192);      //    131,072 B
    unsigned short* w1p = (unsigned short*)(ws + 44171264);      //     16,384 B
    unsigned short* E   = (unsigned short*)(ws + 44187648);      // 41,943,040 B  (total ~86.1 MB)

    hipLaunchKernelGGL(k_cvt_x, dim3(2048), dim3(256), 0, stream, x, xb, (B_SZ * D1_IN * T_DIM) / 4);
    hipLaunchKernelGGL(k_transpose_bf, dim3(32, 32), dim3(256), 0, stream, W, wt, 1024, 1024);
    hipLaunchKernelGGL(k_transpose_bf, dim3(2, 32), dim3(256), 0, stream, W2, w2t, 1024, 64);
    hipLaunchKernelGGL(k_w1pad, dim3(1), dim3(256), 0, stream, W1, w1p);
    hipLaunchKernelGGL(k_gemm1, dim3(1280), dim3(256), 0, stream, xb, wt, E);
    hipLaunchKernelGGL(k_softmax, dim3(5120), dim3(256), 0, stream, E, A);
    hipLaunchKernelGGL(k_fused, dim3(512), dim3(256), 0, stream, x, w1p, A, w2t, Bias, lam, out);
}

// Round 2
// 194.576 us; speedup vs baseline: 1.1134x; 1.1134x over previous
//
#include <hip/hip_runtime.h>
#include <cstdint>
#include <cstddef>

typedef __attribute__((ext_vector_type(8))) short bf16x8;
typedef __attribute__((ext_vector_type(4))) float f32x4;
typedef __attribute__((ext_vector_type(8))) unsigned short ushort8;
typedef __attribute__((ext_vector_type(4))) unsigned short ushort4v;

#define B_SZ   512
#define D1_IN  40
#define T_DIM  1024
#define D1_OUT 120
#define D2_OUT 64
#define M_ROWS (B_SZ * D1_IN)            // 20480
#define OUT0_SZ (B_SZ * D1_OUT * D2_OUT) // 3932160

// per-bn bitmask of nonzero 32-wide k-steps of W (general sparsity skip)
__device__ unsigned int g_wmask[8];

// ---- helpers ----
__device__ __forceinline__ unsigned short f2bf(float f) {
    unsigned int u = __float_as_uint(f);
    u += 0x7FFFu + ((u >> 16) & 1u);   // RNE
    return (unsigned short)(u >> 16);
}
__device__ __forceinline__ float bf2f(unsigned short h) {
    return __uint_as_float(((unsigned int)h) << 16);
}
__device__ __forceinline__ void gld16(const unsigned short* g, unsigned short* l) {
    __builtin_amdgcn_global_load_lds(
        (const __attribute__((address_space(1))) unsigned int*)g,
        (__attribute__((address_space(3))) unsigned int*)l, 16, 0, 0);
}

// ---- convert x (fp32) -> xb (bf16) ----
__global__ __launch_bounds__(256) void k_cvt_x(const float* __restrict__ X,
                                               unsigned short* __restrict__ Y, int n4) {
    int stride = gridDim.x * blockDim.x;
    for (int i = blockIdx.x * blockDim.x + threadIdx.x; i < n4; i += stride) {
        float4 v = ((const float4*)X)[i];
        ushort4v o;
        o.x = f2bf(v.x); o.y = f2bf(v.y); o.z = f2bf(v.z); o.w = f2bf(v.w);
        ((ushort4v*)Y)[i] = o;
    }
}

// ---- transpose src(RxC fp32) -> dst(CxR bf16) ----
__global__ __launch_bounds__(256) void k_transpose_bf(const float* __restrict__ src,
                                                      unsigned short* __restrict__ dst,
                                                      int R, int C) {
    __shared__ float tile[32][33];
    int c0 = blockIdx.x * 32, r0 = blockIdx.y * 32;
    int tx = threadIdx.x & 31, ty = threadIdx.x >> 5;  // 32x8
    #pragma unroll
    for (int i = 0; i < 4; i++)
        tile[ty + i * 8][tx] = src[(size_t)(r0 + ty + i * 8) * C + c0 + tx];
    __syncthreads();
    #pragma unroll
    for (int i = 0; i < 4; i++)
        dst[(size_t)(c0 + ty + i * 8) * R + r0 + tx] = f2bf(tile[tx][ty + i * 8]);
}

// ---- W1 (120x40 fp32) -> padded bf16 (128x64, zeros) ----
__global__ __launch_bounds__(256) void k_w1pad(const float* __restrict__ W1,
                                               unsigned short* __restrict__ w1p) {
    for (int i = threadIdx.x; i < 128 * 64; i += 256) {
        int o = i >> 6, f = i & 63;
        w1p[i] = (o < D1_OUT && f < D1_IN) ? f2bf(W1[o * D1_IN + f]) : (unsigned short)0;
    }
}

// ---- W nonzero-panel mask: block bn scans W[:, bn*128..+128) ----
__global__ __launch_bounds__(256) void k_wmask(const float* __restrict__ W) {
    __shared__ unsigned int sm[256];
    int bn = blockIdx.x, t = threadIdx.x;
    int rbase = t >> 5;            // 0..7
    int c0 = (t & 31) * 4;         // 0..124
    unsigned int m = 0;
    for (int ks = 0; ks < 32; ks++) {
        bool nz = false;
        #pragma unroll
        for (int i = 0; i < 4; i++) {
            int r = ks * 32 + rbase + i * 8;
            float4 v = *(const float4*)(W + (size_t)r * T_DIM + bn * 128 + c0);
            nz |= (v.x != 0.f) | (v.y != 0.f) | (v.z != 0.f) | (v.w != 0.f);
        }
        if (nz) m |= (1u << ks);
    }
    sm[t] = m;
    __syncthreads();
    if (t == 0) {
        unsigned int acc = 0;
        for (int i = 0; i < 256; i++) acc |= sm[i];
        g_wmask[bn] = acc;
    }
}

// ---- GEMM1: E(bf16) = xb(20480x1024) @ Wt^T, skipping all-zero W k-panels ----
__global__ __launch_bounds__(256) void k_gemm1(const unsigned short* __restrict__ xb,
                                               const unsigned short* __restrict__ wt,
                                               unsigned short* __restrict__ E) {
    __shared__ unsigned short As[128 * 32];
    __shared__ unsigned short Bs[128 * 32];
    int bm = blockIdx.x >> 3, bn = blockIdx.x & 7;   // 160 x 8
    int tid = threadIdx.x, l = tid & 63, w = tid >> 6;
    int wr = w >> 1, wc = w & 1;
    int rr = l & 15, q = l >> 4;
    unsigned int mask = g_wmask[bn];
    f32x4 acc[4][4] = {};
    for (int ks = 0; ks < 32; ks++) {
        if (!((mask >> ks) & 1u)) continue;
        int k0 = ks * 32;
        __syncthreads();
        #pragma unroll
        for (int i = 0; i < 2; i++) {
            int ch = i * 256 + tid;            // 0..511, linear in lane per wave
            int r = ch >> 2, c = ch & 3;
            gld16(xb + (size_t)(bm * 128 + r) * T_DIM + k0 + c * 8, &As[ch * 8]);
            gld16(wt + (size_t)(bn * 128 + r) * T_DIM + k0 + c * 8, &Bs[ch * 8]);
        }
        __syncthreads();
        bf16x8 a[4], b[4];
        #pragma unroll
        for (int m = 0; m < 4; m++) a[m] = *(const bf16x8*)&As[(wr * 64 + m * 16 + rr) * 32 + q * 8];
        #pragma unroll
        for (int n = 0; n < 4; n++) b[n] = *(const bf16x8*)&Bs[(wc * 64 + n * 16 + rr) * 32 + q * 8];
        #pragma unroll
        for (int m = 0; m < 4; m++)
            #pragma unroll
            for (int n = 0; n < 4; n++)
                acc[m][n] = __builtin_amdgcn_mfma_f32_16x16x32_bf16(a[m], b[n], acc[m][n], 0, 0, 0);
    }
    #pragma unroll
    for (int m = 0; m < 4; m++)
        #pragma unroll
        for (int n = 0; n < 4; n++)
            #pragma unroll
            for (int j = 0; j < 4; j++) {
                int row = wr * 64 + m * 16 + q * 4 + j;
                int col = wc * 64 + n * 16 + rr;
                E[(size_t)(bm * 128 + row) * T_DIM + bn * 128 + col] = f2bf(acc[m][n][j]);
            }
}

// ---- softmax per row: A(fp32, to d_out) = softmax(E bf16) ----
__global__ __launch_bounds__(256) void k_softmax(const unsigned short* __restrict__ E,
                                                 float* __restrict__ A) {
    int row = blockIdx.x * 4 + (threadIdx.x >> 6);
    int l = threadIdx.x & 63;
    const ushort8* pe = (const ushort8*)(E + (size_t)row * T_DIM + l * 16);
    ushort8 u0 = pe[0], u1 = pe[1];
    float v[16];
    #pragma unroll
    for (int j = 0; j < 8; j++) { v[j] = bf2f(u0[j]); v[8 + j] = bf2f(u1[j]); }
    float m = v[0];
    #pragma unroll
    for (int j = 1; j < 16; j++) m = fmaxf(m, v[j]);
    for (int off = 32; off > 0; off >>= 1) m = fmaxf(m, __shfl_xor(m, off));
    float s = 0.f;
    #pragma unroll
    for (int j = 0; j < 16; j++) { v[j] = __expf(v[j] - m); s += v[j]; }
    for (int off = 32; off > 0; off >>= 1) s += __shfl_xor(s, off);
    float inv = 1.f / s;
    float4* pa = (float4*)(A + (size_t)row * T_DIM + l * 16);
    #pragma unroll
    for (int j = 0; j < 4; j++) {
        float4 o;
        o.x = v[j * 4 + 0] * inv; o.y = v[j * 4 + 1] * inv;
        o.z = v[j * 4 + 2] * inv; o.w = v[j * 4 + 3] * inv;
        pa[j] = o;
    }
}

// ---- fused: X_bar = W1@x[b] (MFMA), gate from LDS, out = X_tilde@W2 + B, relu ----
__global__ __launch_bounds__(512) void k_fused(const unsigned short* __restrict__ xb,
                                               const unsigned short* __restrict__ w1p,
                                               const float* __restrict__ A,
                                               const unsigned short* __restrict__ w2t,
                                               const float* __restrict__ Bias,
                                               const float* __restrict__ lamp,
                                               float* __restrict__ out) {
    __shared__ unsigned short xst[64 * 72];   // [t][f], f-padded to 72, f>=40 zero
    __shared__ float ast[40 * 73];            // gate chunk [f][t], stride 73
    __shared__ unsigned short xtl[128 * 72];  // [row][t]
    int b = blockIdx.x;
    int tid = threadIdx.x, l = tid & 63, w = tid >> 6;   // 8 waves, 16 rows each
    int rr = l & 15, q = l >> 4;
    float lam = fminf(fmaxf(lamp[0], 0.f), 1.f), oml = 1.f - lam;
    // W1 A-fragments for this wave's 16-row strip (constant over chunks)
    bf16x8 aw[2];
    #pragma unroll
    for (int ks = 0; ks < 2; ks++)
        aw[ks] = *(const bf16x8*)(w1p + (w * 16 + rr) * 64 + ks * 32 + q * 8);
    int rowv[4], rowm[4];
    #pragma unroll
    for (int j = 0; j < 4; j++) { rowv[j] = w * 16 + q * 4 + j; rowm[j] = rowv[j] % D1_IN; }
    f32x4 acc2[4] = {};
    for (int i = tid; i < 64 * 72; i += 512) xst[i] = 0;  // zero pads persist
    const unsigned short* xbb = xb + (size_t)b * D1_IN * T_DIM;
    const float* Ab = A + (size_t)b * D1_IN * T_DIM;
    for (int tc = 0; tc < 16; tc++) {
        int t0 = tc * 64;
        __syncthreads();   // prev-chunk LDS reads done
        // stage x chunk transposed to [t][f] (bf16 source)
        if (tid < 320) {
            int f = tid >> 3, k8 = tid & 7;
            ushort8 v = *(const ushort8*)(xbb + f * T_DIM + t0 + k8 * 8);
            #pragma unroll
            for (int i = 0; i < 8; i++) xst[(k8 * 8 + i) * 72 + f] = v[i];
        }
        // stage gate chunk: g = lam*A + (1-lam)
        for (int idx = tid; idx < 640; idx += 512) {
            int f = idx >> 4, t4 = idx & 15;
            float4 av = *(const float4*)(Ab + (size_t)f * T_DIM + t0 + t4 * 4);
            ast[f * 73 + t4 * 4 + 0] = lam * av.x + oml;
            ast[f * 73 + t4 * 4 + 1] = lam * av.y + oml;
            ast[f * 73 + t4 * 4 + 2] = lam * av.z + oml;
            ast[f * 73 + t4 * 4 + 3] = lam * av.w + oml;
        }
        __syncthreads();
        // X_bar strip via MFMA
        f32x4 acc1[4] = {};
        #pragma unroll
        for (int ni = 0; ni < 4; ni++)
            #pragma unroll
            for (int ks = 0; ks < 2; ks++) {
                bf16x8 bx = *(const bf16x8*)&xst[(ni * 16 + rr) * 72 + ks * 32 + q * 8];
                acc1[ni] = __builtin_amdgcn_mfma_f32_16x16x32_bf16(aw[ks], bx, acc1[ni], 0, 0, 0);
            }
        // gate (LDS) + write X_tilde rows (same-wave RAW: DS in-order per wave)
        #pragma unroll
        for (int ni = 0; ni < 4; ni++)
            #pragma unroll
            for (int j = 0; j < 4; j++) {
                int t = ni * 16 + rr;
                float g = ast[rowm[j] * 73 + t];
                xtl[rowv[j] * 72 + t] = f2bf(acc1[ni][j] * g);
            }
        // GEMM2 accumulate over this t-chunk
        #pragma unroll
        for (int ks2 = 0; ks2 < 2; ks2++) {
            bf16x8 a2 = *(const bf16x8*)&xtl[(w * 16 + rr) * 72 + ks2 * 32 + q * 8];
            #pragma unroll
            for (int ni = 0; ni < 4; ni++) {
                bf16x8 b2 = *(const bf16x8*)(w2t + (size_t)(ni * 16 + rr) * T_DIM + t0 + ks2 * 32 + q * 8);
                acc2[ni] = __builtin_amdgcn_mfma_f32_16x16x32_bf16(a2, b2, acc2[ni], 0, 0, 0);
            }
        }
    }
    #pragma unroll
    for (int ni = 0; ni < 4; ni++)
        #pragma unroll
        for (int j = 0; j < 4; j++) {
            int row = rowv[j];
            if (row < D1_OUT) {
                int col = ni * 16 + rr;
                float v = acc2[ni][j] + Bias[row * D2_OUT + col];
                out[((size_t)b * D1_OUT + row) * D2_OUT + col] = fmaxf(v, 0.f);
            }
        }
}

extern "C" void kernel_launch(void* const* d_in, const int* in_sizes, int n_in,
                              void* d_out, int out_size, void* d_ws, size_t ws_size,
                              hipStream_t stream) {
    const float* x    = (const float*)d_in[0];
    const float* W1   = (const float*)d_in[1];
    const float* W    = (const float*)d_in[2];
    const float* W2   = (const float*)d_in[3];
    const float* Bias = (const float*)d_in[4];
    const float* lam  = (const float*)d_in[5];
    float* out = (float*)d_out;
    float* A   = out + OUT0_SZ;                    // second output region

    char* ws = (char*)d_ws;
    unsigned short* xb  = (unsigned short*)(ws);                 // 41,943,040 B
    unsigned short* wt  = (unsigned short*)(ws + 41943040);      //  2,097,152 B
    unsigned short* w2t = (unsigned short*)(ws + 44040192);      //    131,072 B
    unsigned short* w1p = (unsigned short*)(ws + 44171264);      //     16,384 B
    unsigned short* E   = (unsigned short*)(ws + 44187648);      // 41,943,040 B  (total ~86.1 MB)

    hipLaunchKernelGGL(k_cvt_x, dim3(2048), dim3(256), 0, stream, x, xb, (B_SZ * D1_IN * T_DIM) / 4);
    hipLaunchKernelGGL(k_transpose_bf, dim3(32, 32), dim3(256), 0, stream, W, wt, 1024, 1024);
    hipLaunchKernelGGL(k_transpose_bf, dim3(2, 32), dim3(256), 0, stream, W2, w2t, 1024, 64);
    hipLaunchKernelGGL(k_w1pad, dim3(1), dim3(256), 0, stream, W1, w1p);
    hipLaunchKernelGGL(k_wmask, dim3(8), dim3(256), 0, stream, W);
    hipLaunchKernelGGL(k_gemm1, dim3(1280), dim3(256), 0, stream, xb, wt, E);
    hipLaunchKernelGGL(k_softmax, dim3(5120), dim3(256), 0, stream, E, A);
    hipLaunchKernelGGL(k_fused, dim3(512), dim3(512), 0, stream, xb, w1p, A, w2t, Bias, lam, out);
}

// Round 3
// 179.147 us; speedup vs baseline: 1.2093x; 1.0861x over previous
//
#include <hip/hip_runtime.h>
#include <cstdint>
#include <cstddef>

typedef __attribute__((ext_vector_type(8))) short bf16x8;
typedef __attribute__((ext_vector_type(4))) float f32x4;
typedef __attribute__((ext_vector_type(8))) unsigned short ushort8;
typedef __attribute__((ext_vector_type(4))) unsigned short ushort4v;

#define B_SZ   512
#define D1_IN  40
#define T_DIM  1024
#define D1_OUT 120
#define D2_OUT 64
#define OUT0_SZ (B_SZ * D1_OUT * D2_OUT) // 3932160

// per-bn bitmask of nonzero 32-wide k-steps of W (general sparsity skip)
__device__ unsigned int g_wmask[8];

// ---- helpers ----
__device__ __forceinline__ unsigned short f2bf(float f) {
    unsigned int u = __float_as_uint(f);
    u += 0x7FFFu + ((u >> 16) & 1u);   // RNE
    return (unsigned short)(u >> 16);
}
__device__ __forceinline__ float bf2f(unsigned short h) {
    return __uint_as_float(((unsigned int)h) << 16);
}
__device__ __forceinline__ void gld16v(const void* g, void* l) {
    __builtin_amdgcn_global_load_lds(
        (const __attribute__((address_space(1))) unsigned int*)g,
        (__attribute__((address_space(3))) unsigned int*)l, 16, 0, 0);
}

// ---- merged small prep: W2 transpose (blocks 0..63), wmask (64..71), w1pad (72) ----
__global__ __launch_bounds__(256) void k_prep_small(const float* __restrict__ W1,
                                                    const float* __restrict__ W,
                                                    const float* __restrict__ W2,
                                                    unsigned short* __restrict__ w2t,
                                                    unsigned short* __restrict__ w1p) {
    int blk = blockIdx.x, tid = threadIdx.x;
    if (blk < 64) {
        // transpose W2 (1024x64 fp32) -> w2t (64x1024 bf16)
        __shared__ float tile[32][33];
        int c0 = (blk & 1) * 32, r0 = (blk >> 1) * 32;
        int tx = tid & 31, ty = tid >> 5;
        #pragma unroll
        for (int i = 0; i < 4; i++)
            tile[ty + i * 8][tx] = W2[(size_t)(r0 + ty + i * 8) * D2_OUT + c0 + tx];
        __syncthreads();
        #pragma unroll
        for (int i = 0; i < 4; i++)
            w2t[(size_t)(c0 + ty + i * 8) * T_DIM + r0 + tx] = f2bf(tile[tx][ty + i * 8]);
    } else if (blk < 72) {
        // wmask: panel bn = blk-64 of W
        __shared__ unsigned int sm[256];
        int bn = blk - 64;
        int rbase = tid >> 5, c0 = (tid & 31) * 4;
        unsigned int m = 0;
        for (int ks = 0; ks < 32; ks++) {
            bool nz = false;
            #pragma unroll
            for (int i = 0; i < 4; i++) {
                int r = ks * 32 + rbase + i * 8;
                float4 v = *(const float4*)(W + (size_t)r * T_DIM + bn * 128 + c0);
                nz |= (v.x != 0.f) | (v.y != 0.f) | (v.z != 0.f) | (v.w != 0.f);
            }
            if (nz) m |= (1u << ks);
        }
        sm[tid] = m;
        __syncthreads();
        if (tid == 0) {
            unsigned int acc = 0;
            for (int i = 0; i < 256; i++) acc |= sm[i];
            g_wmask[bn] = acc;
        }
    } else {
        // w1pad: W1 (120x40) -> 128x64 bf16 zero-padded
        for (int i = tid; i < 128 * 64; i += 256) {
            int o = i >> 6, f = i & 63;
            w1p[i] = (o < D1_OUT && f < D1_IN) ? f2bf(W1[o * D1_IN + f]) : (unsigned short)0;
        }
    }
}

// ---- transpose W (1024x1024 fp32) -> wt (1024x1024 bf16) ----
__global__ __launch_bounds__(256) void k_transpose_w(const float* __restrict__ src,
                                                     unsigned short* __restrict__ dst) {
    __shared__ float tile[32][33];
    int c0 = blockIdx.x * 32, r0 = blockIdx.y * 32;
    int tx = threadIdx.x & 31, ty = threadIdx.x >> 5;
    #pragma unroll
    for (int i = 0; i < 4; i++)
        tile[ty + i * 8][tx] = src[(size_t)(r0 + ty + i * 8) * T_DIM + c0 + tx];
    __syncthreads();
    #pragma unroll
    for (int i = 0; i < 4; i++)
        dst[(size_t)(c0 + ty + i * 8) * T_DIM + r0 + tx] = f2bf(tile[tx][ty + i * 8]);
}

// ---- GEMM1: E(bf16) = x(20480x1024 fp32, cvt on stage) @ Wt^T, masked k-steps ----
__global__ __launch_bounds__(256) void k_gemm1(const float* __restrict__ x,
                                               const unsigned short* __restrict__ wt,
                                               unsigned short* __restrict__ E) {
    __shared__ unsigned short As[128 * 40];   // stride 40 (pad) bf16
    __shared__ unsigned short Bs[128 * 32];
    int bm = blockIdx.x >> 3, bn = blockIdx.x & 7;   // 160 x 8
    int tid = threadIdx.x, l = tid & 63, w = tid >> 6;
    int wr = w >> 1, wc = w & 1;
    int rr = l & 15, q = l >> 4;
    unsigned int mask = g_wmask[bn];
    f32x4 acc[4][4] = {};
    for (int ks = 0; ks < 32; ks++) {
        if (!((mask >> ks) & 1u)) continue;
        int k0 = ks * 32;
        __syncthreads();
        // A-panel: x fp32 -> bf16 LDS (reg-staged, padded stride)
        #pragma unroll
        for (int i = 0; i < 4; i++) {
            int idx = i * 256 + tid;
            int r = idx >> 3, c4 = idx & 7;
            float4 v = *(const float4*)(x + (size_t)(bm * 128 + r) * T_DIM + k0 + c4 * 4);
            ushort4v o;
            o.x = f2bf(v.x); o.y = f2bf(v.y); o.z = f2bf(v.z); o.w = f2bf(v.w);
            *(ushort4v*)&As[r * 40 + c4 * 4] = o;
        }
        // B-panel: wt bf16 direct-to-LDS
        #pragma unroll
        for (int i = 0; i < 2; i++) {
            int ch = i * 256 + tid;
            int r = ch >> 2, c = ch & 3;
            gld16v(wt + (size_t)(bn * 128 + r) * T_DIM + k0 + c * 8, &Bs[ch * 8]);
        }
        __syncthreads();
        bf16x8 a[4], b[4];
        #pragma unroll
        for (int m = 0; m < 4; m++) a[m] = *(const bf16x8*)&As[(wr * 64 + m * 16 + rr) * 40 + q * 8];
        #pragma unroll
        for (int n = 0; n < 4; n++) b[n] = *(const bf16x8*)&Bs[(wc * 64 + n * 16 + rr) * 32 + q * 8];
        #pragma unroll
        for (int m = 0; m < 4; m++)
            #pragma unroll
            for (int n = 0; n < 4; n++)
                acc[m][n] = __builtin_amdgcn_mfma_f32_16x16x32_bf16(a[m], b[n], acc[m][n], 0, 0, 0);
    }
    #pragma unroll
    for (int m = 0; m < 4; m++)
        #pragma unroll
        for (int n = 0; n < 4; n++)
            #pragma unroll
            for (int j = 0; j < 4; j++) {
                int row = wr * 64 + m * 16 + q * 4 + j;
                int col = wc * 64 + n * 16 + rr;
                E[(size_t)(bm * 128 + row) * T_DIM + bn * 128 + col] = f2bf(acc[m][n][j]);
            }
}

// ---- softmax per row: A(fp32, to d_out) = softmax(E bf16) ----
__global__ __launch_bounds__(256) void k_softmax(const unsigned short* __restrict__ E,
                                                 float* __restrict__ A) {
    int row = blockIdx.x * 4 + (threadIdx.x >> 6);
    int l = threadIdx.x & 63;
    const ushort8* pe = (const ushort8*)(E + (size_t)row * T_DIM + l * 16);
    ushort8 u0 = pe[0], u1 = pe[1];
    float v[16];
    #pragma unroll
    for (int j = 0; j < 8; j++) { v[j] = bf2f(u0[j]); v[8 + j] = bf2f(u1[j]); }
    float m = v[0];
    #pragma unroll
    for (int j = 1; j < 16; j++) m = fmaxf(m, v[j]);
    for (int off = 32; off > 0; off >>= 1) m = fmaxf(m, __shfl_xor(m, off));
    float s = 0.f;
    #pragma unroll
    for (int j = 0; j < 16; j++) { v[j] = __expf(v[j] - m); s += v[j]; }
    for (int off = 32; off > 0; off >>= 1) s += __shfl_xor(s, off);
    float inv = 1.f / s;
    float4* pa = (float4*)(A + (size_t)row * T_DIM + l * 16);
    #pragma unroll
    for (int j = 0; j < 4; j++) {
        float4 o;
        o.x = v[j * 4 + 0] * inv; o.y = v[j * 4 + 1] * inv;
        o.z = v[j * 4 + 2] * inv; o.w = v[j * 4 + 3] * inv;
        pa[j] = o;
    }
}

// ---- prepxT: x (fp32 [b][f][t]) -> xbT (bf16 [b][t][64], f-padded, block-swizzled) ----
// storage: row t holds element f at position ((f>>3) ^ (t&7))*8 + (f&7)
__global__ __launch_bounds__(256) void k_prepxT(const float* __restrict__ x,
                                                unsigned short* __restrict__ xbT) {
    __shared__ unsigned short tl[64 * 72];
    int b = blockIdx.x >> 4, tc = blockIdx.x & 15, t0 = tc * 64;
    int tid = threadIdx.x;
    for (int i = tid; i < 64 * 72; i += 256) tl[i] = 0;
    __syncthreads();
    for (int i = tid; i < 640; i += 256) {
        int f = i >> 4, t4 = (i & 15) * 4;
        float4 v = *(const float4*)(x + ((size_t)b * D1_IN + f) * T_DIM + t0 + t4);
        int blk = f >> 3, fl = f & 7;
        const float* vp = &v.x;
        #pragma unroll
        for (int j = 0; j < 4; j++) {
            int t = t4 + j;
            tl[t * 72 + (((blk ^ (t & 7)) << 3) + fl)] = f2bf(vp[j]);
        }
    }
    __syncthreads();
    int r = tid >> 2, p = tid & 3;
    ushort8 u0 = *(const ushort8*)&tl[r * 72 + p * 16];
    ushort8 u1 = *(const ushort8*)&tl[r * 72 + p * 16 + 8];
    size_t orow = ((size_t)b * T_DIM + t0 + r) * 64;
    *(ushort8*)(xbT + orow + p * 16) = u0;
    *(ushort8*)(xbT + orow + p * 16 + 8) = u1;
}

// ---- fused: X_bar = W1@x[b] (MFMA), gate, out = X_tilde@W2 + B, relu ----
// 2-phase double-buffered: stage chunk t+1 via global_load_lds, compute chunk t, 1 barrier
__global__ __launch_bounds__(512) void k_fused(const unsigned short* __restrict__ xbT,
                                               const unsigned short* __restrict__ w1p,
                                               const float* __restrict__ A,
                                               const unsigned short* __restrict__ w2t,
                                               const float* __restrict__ Bias,
                                               const float* __restrict__ lamp,
                                               float* __restrict__ out) {
    __shared__ unsigned short xst[2][64 * 64];  // swizzled x chunk [t][f-blocks]
    __shared__ float gst[2][40 * 64];           // A chunk [f][t] fp32 (gld16 linear)
    __shared__ unsigned short xtl[128 * 68];    // X_tilde [o][t], stride 68
    int b = blockIdx.x;
    int tid = threadIdx.x, l = tid & 63, w = tid >> 6;   // 8 waves, 16 o-rows each
    int rr = l & 15, q = l >> 4;
    float lam = fminf(fmaxf(lamp[0], 0.f), 1.f), oml = 1.f - lam;
    bf16x8 aw[2];
    #pragma unroll
    for (int ks = 0; ks < 2; ks++)
        aw[ks] = *(const bf16x8*)(w1p + (w * 16 + rr) * 64 + ks * 32 + q * 8);
    int rowv[4], rowm[4];
    #pragma unroll
    for (int j = 0; j < 4; j++) { rowv[j] = w * 16 + q * 4 + j; rowm[j] = rowv[j] % D1_IN; }
    f32x4 acc2[4] = {};
    const unsigned short* xTb = xbT + (size_t)b * T_DIM * 64;
    const float* Ab = A + (size_t)b * D1_IN * T_DIM;

    // stage chunk t0 into buffer buf
    auto STAGE = [&](int buf, int t0) {
        // xst: wave w stages rows w*8..w*8+7 (1 KB, lane-linear = global row order)
        gld16v(xTb + ((size_t)(t0 + w * 8 + (l >> 3))) * 64 + (l & 7) * 8,
               &xst[buf][w * 8 * 64]);
        // gate: 10 segments of 4 fp32 rows; waves 0..7 one, waves 0..1 a second
        gld16v(Ab + (size_t)(w * 4 + (l >> 4)) * T_DIM + t0 + (l & 15) * 4,
               &gst[buf][w * 4 * 64]);
        if (w < 2)
            gld16v(Ab + (size_t)((8 + w) * 4 + (l >> 4)) * T_DIM + t0 + (l & 15) * 4,
                   &gst[buf][(8 + w) * 4 * 64]);
    };

    STAGE(0, 0);
    __syncthreads();   // drains vmcnt(0) before barrier (compiler-inserted)
    for (int tc = 0; tc < 16; tc++) {
        int cur = tc & 1, t0 = tc * 64;
        if (tc < 15) STAGE(cur ^ 1, t0 + 64);
        // w2 B-fragments to regs, issued early (consumed at end of chunk)
        bf16x8 b2[2][4];
        #pragma unroll
        for (int ks2 = 0; ks2 < 2; ks2++)
            #pragma unroll
            for (int ni = 0; ni < 4; ni++)
                b2[ks2][ni] = *(const bf16x8*)(w2t + (size_t)(ni * 16 + rr) * T_DIM + t0 + ks2 * 32 + q * 8);
        // X_bar strip via MFMA (swizzled xst read)
        f32x4 acc1[4] = {};
        #pragma unroll
        for (int ni = 0; ni < 4; ni++)
            #pragma unroll
            for (int ks = 0; ks < 2; ks++) {
                bf16x8 bx = *(const bf16x8*)&xst[cur][(ni * 16 + rr) * 64 + (((ks * 4 + q) ^ (rr & 7)) << 3)];
                acc1[ni] = __builtin_amdgcn_mfma_f32_16x16x32_bf16(aw[ks], bx, acc1[ni], 0, 0, 0);
            }
        // gate + write X_tilde rows (same-wave RAW, DS in-order)
        #pragma unroll
        for (int ni = 0; ni < 4; ni++)
            #pragma unroll
            for (int j = 0; j < 4; j++) {
                int t = ni * 16 + rr;
                float g = lam * gst[cur][rowm[j] * 64 + t] + oml;
                xtl[rowv[j] * 68 + t] = f2bf(acc1[ni][j] * g);
            }
        // GEMM2 accumulate
        #pragma unroll
        for (int ks2 = 0; ks2 < 2; ks2++) {
            bf16x8 a2 = *(const bf16x8*)&xtl[(w * 16 + rr) * 68 + ks2 * 32 + q * 8];
            #pragma unroll
            for (int ni = 0; ni < 4; ni++)
                acc2[ni] = __builtin_amdgcn_mfma_f32_16x16x32_bf16(a2, b2[ks2][ni], acc2[ni], 0, 0, 0);
        }
        __syncthreads();   // drains staged gld16 (vmcnt(0)) + protects buffers
    }
    #pragma unroll
    for (int ni = 0; ni < 4; ni++)
        #pragma unroll
        for (int j = 0; j < 4; j++) {
            int row = rowv[j];
            if (row < D1_OUT) {
                int col = ni * 16 + rr;
                float v = acc2[ni][j] + Bias[row * D2_OUT + col];
                out[((size_t)b * D1_OUT + row) * D2_OUT + col] = fmaxf(v, 0.f);
            }
        }
}

extern "C" void kernel_launch(void* const* d_in, const int* in_sizes, int n_in,
                              void* d_out, int out_size, void* d_ws, size_t ws_size,
                              hipStream_t stream) {
    const float* x    = (const float*)d_in[0];
    const float* W1   = (const float*)d_in[1];
    const float* W    = (const float*)d_in[2];
    const float* W2   = (const float*)d_in[3];
    const float* Bias = (const float*)d_in[4];
    const float* lam  = (const float*)d_in[5];
    float* out = (float*)d_out;
    float* A   = out + OUT0_SZ;                    // second output region

    char* ws = (char*)d_ws;
    // region 0 (64 MB): E (first 40 MB) then reused as xbT after softmax
    unsigned short* E   = (unsigned short*)(ws);
    unsigned short* xbT = (unsigned short*)(ws);
    unsigned short* wt  = (unsigned short*)(ws + 67108864);   // 2 MB
    unsigned short* w2t = (unsigned short*)(ws + 69206016);   // 128 KB
    unsigned short* w1p = (unsigned short*)(ws + 69337088);   // 16 KB  (total ~69.4 MB)

    hipLaunchKernelGGL(k_prep_small, dim3(73), dim3(256), 0, stream, W1, W, W2, w2t, w1p);
    hipLaunchKernelGGL(k_transpose_w, dim3(32, 32), dim3(256), 0, stream, W, wt);
    hipLaunchKernelGGL(k_gemm1, dim3(1280), dim3(256), 0, stream, x, wt, E);
    hipLaunchKernelGGL(k_softmax, dim3(5120), dim3(256), 0, stream, E, A);
    hipLaunchKernelGGL(k_prepxT, dim3(8192), dim3(256), 0, stream, x, xbT);
    hipLaunchKernelGGL(k_fused, dim3(512), dim3(512), 0, stream, xbT, w1p, A, w2t, Bias, lam, out);
}